// Round 14
// baseline (213.172 us; speedup 1.0000x reference)
//
#include <hip/hip_runtime.h>
#include <hip/hip_bf16.h>

#define KDIM 4096
#define NKT 128                  // K-tiles of 32
#define NELEM16 (1u << 24)

typedef float f32x4 __attribute__((ext_vector_type(4)));
typedef short bf16x8 __attribute__((ext_vector_type(8)));

typedef const __attribute__((address_space(1))) unsigned int g_u32;
typedef __attribute__((address_space(3))) unsigned int l_u32;

__device__ __forceinline__ void gload_lds16(const void* g, void* l) {
    __builtin_amdgcn_global_load_lds((g_u32*)g, (l_u32*)l, 16, 0, 0);
}

__device__ __forceinline__ unsigned int pack_bf16x2(float lo, float hi) {
    __hip_bfloat162 h = __float22bfloat162_rn(float2{lo, hi});
    union { __hip_bfloat162 h; unsigned int u; } c; c.h = h; return c.u;
}

// ---- pack ----
// A-image (x): [mt16][kt128][rl256][cp4][8e], content x[mt*256+rl][kt*32+(cp^((rl>>1)&3))*8..]
//   (corrected swizzle: with 64-B rows, banks base = (rl&1)*16; chunk XOR on (rl>>1)&3
//    spreads the 8 even / 8 odd lanes of a quarter-wave over 4 chunks -> 2-way, free)
// B-frag image (W): [nt32][kt128][nf8][lane64][8e], content
//   W[nt*128+nf*16+(lane&15)][kt*32+(lane>>4)*8+e]  (fragment-contiguous, coalesced)
__global__ __launch_bounds__(256)
void pack4(const float* __restrict__ x, const float* __restrict__ W,
           unsigned short* __restrict__ xb, unsigned short* __restrict__ wb)
{
    const unsigned int stride = gridDim.x * blockDim.x;
    for (unsigned int i = blockIdx.x * blockDim.x + threadIdx.x; i < (1u << 22); i += stride) {
        const float* __restrict__ in;
        unsigned short* __restrict__ out;
        unsigned int row, col, j;
        if (i < (1u << 21)) {                    // A-image
            j = i;
            const unsigned int cp = j & 3;
            const unsigned int rl = (j >> 2) & 255;
            const unsigned int kt = (j >> 10) & 127;
            const unsigned int mt = j >> 17;
            row = mt * 256 + rl;
            col = kt * 32 + (cp ^ ((rl >> 1) & 3)) * 8;
            in = x; out = xb;
        } else {                                 // B-frag image
            j = i - (1u << 21);
            const unsigned int lane = j & 63;
            const unsigned int nf   = (j >> 6) & 7;
            const unsigned int kt   = (j >> 9) & 127;
            const unsigned int nt   = j >> 16;
            row = nt * 128 + nf * 16 + (lane & 15);
            col = kt * 32 + (lane >> 4) * 8;
            in = W; out = wb;
        }
        const float4* sp = (const float4*)(in + (size_t)row * KDIM + col);
        const float4 a = sp[0], b = sp[1];
        uint4 o;
        o.x = pack_bf16x2(a.x, a.y); o.y = pack_bf16x2(a.z, a.w);
        o.z = pack_bf16x2(b.x, b.y); o.w = pack_bf16x2(b.z, b.w);
        *(uint4*)(out + (size_t)j * 8) = o;
    }
}

// ---- 256x128 GEMM, BK=32, tri-buffer A-only LDS (48 KB), B global-direct,
//      2 blocks/CU co-residency ----
#define STAGE3(kt, BUFE)                                                        \
    {                                                                           \
        const unsigned short* ga = Abase + (size_t)(kt) * 8192 + wid * 1024 + lane * 8; \
        gload_lds16(ga,       &lds[(BUFE) + wid * 1024]);                       \
        gload_lds16(ga + 512, &lds[(BUFE) + wid * 1024 + 512]);                 \
    }

#define READ_A(BUFE)                                                            \
    _Pragma("unroll") for (int mf = 0; mf < 4; ++mf)                            \
        afr[mf] = *(const bf16x8*)&lds[(BUFE) + rdA + mf * 512];

#define LOAD_B(dst, t)                                                          \
    _Pragma("unroll") for (int n = 0; n < 4; ++n)                               \
        dst[n] = *(const bf16x8*)&Bb[(size_t)(t) * 4096 + (wn * 4 + n) * 512 + lane * 8];

#define MFMA16(BC)                                                              \
    __builtin_amdgcn_s_setprio(1);                                              \
    _Pragma("unroll") for (int mf = 0; mf < 4; ++mf)                            \
      _Pragma("unroll") for (int nf = 0; nf < 4; ++nf)                          \
        acc[mf][nf] = __builtin_amdgcn_mfma_f32_16x16x32_bf16(                  \
            afr[mf], BC[nf], acc[mf][nf], 0, 0, 0);                             \
    __builtin_amdgcn_s_setprio(0);

// phase(t): [readA(t); loadB(t+1)->nxt; stageA(t+2); MFMA(t) on cur; vmcnt(6); BAR]
// Compiler's pre-MFMA vmcnt for BCUR counts {B(t+1),stage(t+2)} = 6 newer ops ->
// no stall (BCUR issued a full phase earlier). End vmcnt(6) drains stage(t+1)
// exactly (outstanding: stage(t+1), B(t+1), stage(t+2) = 8 -> keep 6). WAR on A
// bufs: stage(t+2) hits buf read at t-1, drained into regs before BAR(t-1).
#define PHASE(t, BUFE, STGE, BCUR, BNXT, VMW)                                   \
    {                                                                           \
        READ_A(BUFE);                                                           \
        if ((t) + 1 < NKT) LOAD_B(BNXT, (t) + 1);                               \
        if ((t) + 2 < NKT) STAGE3((t) + 2, STGE);                               \
        MFMA16(BCUR);                                                           \
        VMW;                                                                    \
        __builtin_amdgcn_s_barrier();                                           \
        __builtin_amdgcn_sched_barrier(0);                                      \
    }

#define VM6 asm volatile("s_waitcnt vmcnt(6)" ::: "memory")
#define VM0 asm volatile("s_waitcnt vmcnt(0)" ::: "memory")

__global__ __launch_bounds__(512, 4)
void gemm_cores(const unsigned short* __restrict__ A,
                const unsigned short* __restrict__ B,
                const float* __restrict__ bias,
                float* __restrict__ out)
{
    __shared__ unsigned short lds[24576];   // 48 KiB: 3 bufs x 16 KB (A only)

    const int tid  = threadIdx.x;
    const int lane = tid & 63;
    const int wid  = tid >> 6;     // 0..7
    const int wm   = wid >> 1;     // 0..3 (64-row slab)
    const int wn   = wid & 1;      // 0..1 (64-col slab)
    const int c15  = lane & 15;
    const int q4   = lane >> 4;

    // 512 blocks = 16(m) x 32(n) tiles; XCD-bijective swizzle (512 % 8 == 0)
    const int bid = blockIdx.x;
    const int wg  = (bid & 7) * 64 + (bid >> 3);
    const int bm  = wg >> 5;       // 0..15
    const int bn  = wg & 31;       // 0..31

    const unsigned short* Abase = A + ((size_t)bm << 20);   // 16KB/kt * 128 kt
    const unsigned short* Bb    = B + ((size_t)bn << 19);   // 128 rows x 4096 k

    const int rdA = (wm * 64 + c15) * 32 + ((q4 ^ ((c15 >> 1) & 3)) * 8);

    f32x4 acc[4][4];
    #pragma unroll
    for (int i = 0; i < 4; ++i)
        #pragma unroll
        for (int j = 0; j < 4; ++j)
            acc[i][j] = (f32x4)0.0f;

    bf16x8 afr[4];
    bf16x8 bE[4], bO[4];    // B banks: even-phase / odd-phase

    // prologue: A tiles 0,1 -> bufs 0,1; B(0) -> even bank
    STAGE3(0, 0);
    STAGE3(1, 8192);
    LOAD_B(bE, 0);
    VM6;                    // drains stage(0); stage(1)+B(0) in flight (B reg-tracked)
    __builtin_amdgcn_s_barrier();
    __builtin_amdgcn_sched_barrier(0);

    // bufs period 3, B banks period 2 -> unroll 6 (126 = 21 * 6), peel 126,127
    for (int tt = 0; tt < 126; tt += 6) {
        PHASE(tt + 0, 0,     16384, bE, bO, VM6);
        PHASE(tt + 1, 8192,  0,     bO, bE, VM6);
        PHASE(tt + 2, 16384, 8192,  bE, bO, VM6);
        PHASE(tt + 3, 0,     16384, bO, bE, VM6);
        PHASE(tt + 4, 8192,  0,     bE, bO, VM6);
        PHASE(tt + 5, 16384, 8192,  bO, bE, VM6);
    }
    PHASE(126, 0, 16384, bE, bO, VM0);   // guards drop stage/loads past end
    READ_A(8192);                         // phase 127 (buf 1)
    MFMA16(bO);

    // Epilogue: bias + maxpool(4 along col) + sum + atomic row add.
    // C/D frag: col = c15, row = q4*4 + r. Wave cols: wn*64 + nf*16 + c15.
    float rs[4][4];
    #pragma unroll
    for (int mf = 0; mf < 4; ++mf)
        #pragma unroll
        for (int r = 0; r < 4; ++r)
            rs[mf][r] = 0.0f;

    #pragma unroll
    for (int nf = 0; nf < 4; ++nf) {
        const float bv = bias[bn * 128 + wn * 64 + nf * 16 + c15];
        #pragma unroll
        for (int mf = 0; mf < 4; ++mf) {
            #pragma unroll
            for (int r = 0; r < 4; ++r) {
                float v = acc[mf][nf][r] + bv;
                v = fmaxf(v, __shfl_xor(v, 1));
                v = fmaxf(v, __shfl_xor(v, 2));
                v += __shfl_xor(v, 4);
                v += __shfl_xor(v, 8);
                rs[mf][r] += v;
            }
        }
    }

    if (c15 == 0) {
        #pragma unroll
        for (int mf = 0; mf < 4; ++mf)
            #pragma unroll
            for (int r = 0; r < 4; ++r) {
                const int row = bm * 256 + wm * 64 + mf * 16 + q4 * 4 + r;
                atomicAdd(&out[row], 0.5f * rs[mf][r]);
            }
    }
}

// ---------------- fallback (round-1 kernel, verified) if d_ws too small ----------------
__global__ __launch_bounds__(256, 2)
void fused_gemm_pool_fallback(const float* __restrict__ x,
                              const float* __restrict__ W,
                              const float* __restrict__ b,
                              float* __restrict__ out)
{
    __shared__ unsigned short As[128][72];
    __shared__ unsigned short Bs[128][72];

    const int tid  = threadIdx.x;
    const int lane = tid & 63;
    const int wid  = tid >> 6;
    const int wm   = wid >> 1;
    const int wn   = wid & 1;

    const int bid = blockIdx.x;
    const int wg  = (bid & 7) * 128 + (bid >> 3);
    const int bm  = wg >> 5;
    const int bn  = wg & 31;

    const int srow = tid >> 4;
    const int scol = tid & 15;

    const float* xbase = x + (size_t)(bm * 128 + srow) * KDIM + scol * 4;
    const float* wbase = W + (size_t)(bn * 128 + srow) * KDIM + scol * 4;

    f32x4 acc[4][4];
    #pragma unroll
    for (int i = 0; i < 4; ++i)
        #pragma unroll
        for (int j = 0; j < 4; ++j)
            acc[i][j] = (f32x4)0.0f;

    float4 ra[8], rb[8];
    #pragma unroll
    for (int p = 0; p < 8; ++p) {
        ra[p] = *(const float4*)(xbase + (size_t)(p * 16) * KDIM);
        rb[p] = *(const float4*)(wbase + (size_t)(p * 16) * KDIM);
    }

    for (int kt = 0; kt < KDIM / 64; ++kt) {
        #pragma unroll
        for (int p = 0; p < 8; ++p) {
            const int r = srow + p * 16;
            uint2 pa, pb;
            pa.x = pack_bf16x2(ra[p].x, ra[p].y);
            pa.y = pack_bf16x2(ra[p].z, ra[p].w);
            pb.x = pack_bf16x2(rb[p].x, rb[p].y);
            pb.y = pack_bf16x2(rb[p].z, rb[p].w);
            *(uint2*)&As[r][scol * 4] = pa;
            *(uint2*)&Bs[r][scol * 4] = pb;
        }
        __syncthreads();

        if (kt + 1 < KDIM / 64) {
            const float* xa = xbase + (size_t)(kt + 1) * 64;
            const float* wa = wbase + (size_t)(kt + 1) * 64;
            #pragma unroll
            for (int p = 0; p < 8; ++p) {
                ra[p] = *(const float4*)(xa + (size_t)(p * 16) * KDIM);
                rb[p] = *(const float4*)(wa + (size_t)(p * 16) * KDIM);
            }
        }

        #pragma unroll
        for (int k0 = 0; k0 < 2; ++k0) {
            const int kk = k0 * 32 + (lane >> 4) * 8;
            bf16x8 af[4], bfr[4];
            #pragma unroll
            for (int mf = 0; mf < 4; ++mf)
                af[mf] = *(const bf16x8*)&As[wm * 64 + mf * 16 + (lane & 15)][kk];
            #pragma unroll
            for (int nf = 0; nf < 4; ++nf)
                bfr[nf] = *(const bf16x8*)&Bs[wn * 64 + nf * 16 + (lane & 15)][kk];
            #pragma unroll
            for (int mf = 0; mf < 4; ++mf)
                #pragma unroll
                for (int nf = 0; nf < 4; ++nf)
                    acc[mf][nf] = __builtin_amdgcn_mfma_f32_16x16x32_bf16(
                        af[mf], bfr[nf], acc[mf][nf], 0, 0, 0);
        }
        __syncthreads();
    }

    float rs[4][4];
    #pragma unroll
    for (int mf = 0; mf < 4; ++mf)
        #pragma unroll
        for (int r = 0; r < 4; ++r)
            rs[mf][r] = 0.0f;

    #pragma unroll
    for (int nf = 0; nf < 4; ++nf) {
        const float bv = b[bn * 128 + wn * 64 + nf * 16 + (lane & 15)];
        #pragma unroll
        for (int mf = 0; mf < 4; ++mf) {
            #pragma unroll
            for (int r = 0; r < 4; ++r) {
                float v = acc[mf][nf][r] + bv;
                v = fmaxf(v, __shfl_xor(v, 1));
                v = fmaxf(v, __shfl_xor(v, 2));
                v += __shfl_xor(v, 4);
                v += __shfl_xor(v, 8);
                rs[mf][r] += v;
            }
        }
    }

    if ((lane & 15) == 0) {
        #pragma unroll
        for (int mf = 0; mf < 4; ++mf)
            #pragma unroll
            for (int r = 0; r < 4; ++r) {
                const int row = bm * 128 + wm * 64 + mf * 16 + (lane >> 4) * 4 + r;
                atomicAdd(&out[row], 0.5f * rs[mf][r]);
            }
    }
}

extern "C" void kernel_launch(void* const* d_in, const int* in_sizes, int n_in,
                              void* d_out, int out_size, void* d_ws, size_t ws_size,
                              hipStream_t stream) {
    const float* x = (const float*)d_in[0];
    const float* W = (const float*)d_in[1];
    const float* b = (const float*)d_in[2];
    float* out = (float*)d_out;

    hipMemsetAsync(out, 0, (size_t)out_size * sizeof(float), stream);

    const size_t need = (size_t)NELEM16 * 2 * sizeof(unsigned short); // 64 MB
    if (ws_size >= need) {
        unsigned short* xb = (unsigned short*)d_ws;
        unsigned short* wb = xb + (size_t)NELEM16;
        pack4<<<dim3(2048), dim3(256), 0, stream>>>(x, W, xb, wb);
        gemm_cores<<<dim3(512), dim3(512), 0, stream>>>(xb, wb, b, out);
    } else {
        fused_gemm_pool_fallback<<<dim3(1024), dim3(256), 0, stream>>>(x, W, b, out);
    }
}